// Round 6
// baseline (625.473 us; speedup 1.0000x reference)
//
#include <hip/hip_runtime.h>
#include <hip/hip_bf16.h>

#define N_NODES 100000
#define FIN 128
#define HID 16
#define NCLS 40
#define NEDGE 3200000
#define NBUCK 391     // ceil(100000/256): 256 nodes per scan block
#define NCHUNK 782    // ceil(NEDGE/4096)
#define W_ROW 144     // swizzled W row stride (floats)

typedef int v4i __attribute__((ext_vector_type(4)));

// f32 -> bf16 (RNE)
__device__ __forceinline__ unsigned short f2b(float f) {
  union { float f; unsigned u; } v;
  v.f = f;
  unsigned r = v.u + 0x7FFFu + ((v.u >> 16) & 1u);
  return (unsigned short)(r >> 16);
}

// accumulate 8 bf16 (one uint4 = 16B) into 8 fp32
__device__ __forceinline__ void accum8(uint4 w, float* a) {
  union { unsigned u; float f; } t;
  t.u = w.x << 16;         a[0] += t.f;
  t.u = w.x & 0xFFFF0000u; a[1] += t.f;
  t.u = w.y << 16;         a[2] += t.f;
  t.u = w.y & 0xFFFF0000u; a[3] += t.f;
  t.u = w.z << 16;         a[4] += t.f;
  t.u = w.z & 0xFFFF0000u; a[5] += t.f;
  t.u = w.w << 16;         a[6] += t.f;
  t.u = w.w & 0xFFFF0000u; a[7] += t.f;
}

// ---------------------------------------------------------------------------
// proj1: 4 lanes per node, W in bank-swizzled LDS, shfl butterfly. (unchanged)
// ---------------------------------------------------------------------------
__global__ __launch_bounds__(256) void proj1_kernel(
    const float* __restrict__ x, const float* __restrict__ W1,
    const float* __restrict__ root1,
    unsigned* __restrict__ xw1b, float* __restrict__ xr1) {
  __shared__ float Wl[32 * W_ROW];  // 18.4 KB

  int tid = threadIdx.x;
  for (int t = tid; t < 32 * FIN; t += 256) {
    int c = t >> 7, k = t & 127;
    float v = (c < 16) ? W1[FIN * HID + k * HID + c] : root1[k * HID + (c - 16)];
    Wl[c * W_ROW + k + ((k >> 5) << 2)] = v;
  }
  __syncthreads();

  int n = blockIdx.x * 64 + (tid >> 2);
  int j = tid & 3;
  bool live = (n < N_NODES);

  float4 xv[8];
  if (live) {
    const float4* xr = (const float4*)(x + (size_t)n * FIN + j * 32);
#pragma unroll
    for (int m = 0; m < 8; ++m) xv[m] = xr[m];
  } else {
#pragma unroll
    for (int m = 0; m < 8; ++m) xv[m] = make_float4(0.f, 0.f, 0.f, 0.f);
  }

  float acc[32];
  const float* wj = Wl + j * 36;
#pragma unroll 4
  for (int c = 0; c < 32; ++c) {
    const float4* wr = (const float4*)(wj + c * W_ROW);
    float s = 0.f;
#pragma unroll
    for (int m = 0; m < 8; ++m) {
      float4 wv = wr[m];
      s += xv[m].x * wv.x + xv[m].y * wv.y + xv[m].z * wv.z + xv[m].w * wv.w;
    }
    acc[c] = s;
  }

#pragma unroll
  for (int c = 0; c < 32; ++c) {
    acc[c] += __shfl_xor(acc[c], 1);
    acc[c] += __shfl_xor(acc[c], 2);
  }
  if (!live) return;

  if (j == 0) {
    uint4 pk;
    pk.x = (unsigned)f2b(acc[0]) | ((unsigned)f2b(acc[1]) << 16);
    pk.y = (unsigned)f2b(acc[2]) | ((unsigned)f2b(acc[3]) << 16);
    pk.z = (unsigned)f2b(acc[4]) | ((unsigned)f2b(acc[5]) << 16);
    pk.w = (unsigned)f2b(acc[6]) | ((unsigned)f2b(acc[7]) << 16);
    *(uint4*)((char*)xw1b + (size_t)n * 32) = pk;
  } else if (j == 1) {
    uint4 pk;
    pk.x = (unsigned)f2b(acc[8]) | ((unsigned)f2b(acc[9]) << 16);
    pk.y = (unsigned)f2b(acc[10]) | ((unsigned)f2b(acc[11]) << 16);
    pk.z = (unsigned)f2b(acc[12]) | ((unsigned)f2b(acc[13]) << 16);
    pk.w = (unsigned)f2b(acc[14]) | ((unsigned)f2b(acc[15]) << 16);
    *(uint4*)((char*)xw1b + (size_t)n * 32 + 16) = pk;
  } else if (j == 2) {
    *(float4*)(xr1 + (size_t)n * 16 + 0) =
        make_float4(acc[16], acc[17], acc[18], acc[19]);
    *(float4*)(xr1 + (size_t)n * 16 + 4) =
        make_float4(acc[20], acc[21], acc[22], acc[23]);
  } else {
    *(float4*)(xr1 + (size_t)n * 16 + 8) =
        make_float4(acc[24], acc[25], acc[26], acc[27]);
    *(float4*)(xr1 + (size_t)n * 16 + 12) =
        make_float4(acc[28], acc[29], acc[30], acc[31]);
  }
}

// ---------------------------------------------------------------------------
// deg: per-node degree via global no-return atomics. int4-vectorized.
// ---------------------------------------------------------------------------
__global__ __launch_bounds__(512) void deg_kernel(
    const int* __restrict__ dst, int* __restrict__ deg) {
  int e0 = blockIdx.x * 4096 + threadIdx.x * 8;
  if (e0 + 8 <= NEDGE) {
    int4 a = *(const int4*)(dst + e0);
    int4 b = *(const int4*)(dst + e0 + 4);
    atomicAdd(&deg[a.x], 1);
    atomicAdd(&deg[a.y], 1);
    atomicAdd(&deg[a.z], 1);
    atomicAdd(&deg[a.w], 1);
    atomicAdd(&deg[b.x], 1);
    atomicAdd(&deg[b.y], 1);
    atomicAdd(&deg[b.z], 1);
    atomicAdd(&deg[b.w], 1);
  } else {
    for (int e = e0; e < NEDGE; ++e) atomicAdd(&deg[dst[e]], 1);
  }
}

// ---------------------------------------------------------------------------
// scanB: per-256-node-block exclusive scan of deg -> local rowptr + bsum.
// ---------------------------------------------------------------------------
__global__ __launch_bounds__(256) void scanB_kernel(
    const int* __restrict__ deg, int* __restrict__ rowptr,
    int* __restrict__ bsum) {
  __shared__ int s[256];
  int n = blockIdx.x * 256 + threadIdx.x;
  int v = (n < N_NODES) ? deg[n] : 0;
  s[threadIdx.x] = v;
  __syncthreads();
  for (int off = 1; off < 256; off <<= 1) {
    int t = (threadIdx.x >= off) ? s[threadIdx.x - off] : 0;
    __syncthreads();
    s[threadIdx.x] += t;
    __syncthreads();
  }
  if (n < N_NODES) rowptr[n] = s[threadIdx.x] - v;  // local exclusive
  if (threadIdx.x == 255) bsum[blockIdx.x] = s[255];
}

// ---------------------------------------------------------------------------
// scanS: exclusive scan of 391 block sums -> boff; sentinel rowptr[N].
// ---------------------------------------------------------------------------
__global__ __launch_bounds__(512) void scanS_kernel(
    const int* __restrict__ bsum, int* __restrict__ boff,
    int* __restrict__ rowptr) {
  __shared__ int s[512];
  int v = (threadIdx.x < NBUCK) ? bsum[threadIdx.x] : 0;
  s[threadIdx.x] = v;
  __syncthreads();
  for (int off = 1; off < 512; off <<= 1) {
    int t = (threadIdx.x >= off) ? s[threadIdx.x - off] : 0;
    __syncthreads();
    s[threadIdx.x] += t;
    __syncthreads();
  }
  if (threadIdx.x < NBUCK) boff[threadIdx.x] = s[threadIdx.x] - v;
  if (threadIdx.x == 0) rowptr[N_NODES] = NEDGE;
}

// ---------------------------------------------------------------------------
// fix: rowptr += block offset; cur = rowptr (scatter cursors).
// ---------------------------------------------------------------------------
__global__ __launch_bounds__(256) void fix_kernel(
    const int* __restrict__ boff, int* __restrict__ rowptr,
    int* __restrict__ cur) {
  int n = blockIdx.x * 256 + threadIdx.x;
  if (n < N_NODES) {
    int r = rowptr[n] + boff[blockIdx.x];
    rowptr[n] = r;
    cur[n] = r;
  }
}

// ---------------------------------------------------------------------------
// scatter: colsrc[cur[dst]++] = src. Direct CSR fill, one pass.
// Replaces partA+sortB (recs round-trip eliminated).
// ---------------------------------------------------------------------------
__global__ __launch_bounds__(512) void scatter_kernel(
    const int* __restrict__ src, const int* __restrict__ dst,
    int* __restrict__ cur, int* __restrict__ colsrc) {
  int e0 = blockIdx.x * 4096 + threadIdx.x * 8;
  if (e0 + 8 <= NEDGE) {
    int4 d0 = *(const int4*)(dst + e0);
    int4 d1 = *(const int4*)(dst + e0 + 4);
    int4 s0 = *(const int4*)(src + e0);
    int4 s1 = *(const int4*)(src + e0 + 4);
    colsrc[atomicAdd(&cur[d0.x], 1)] = s0.x;
    colsrc[atomicAdd(&cur[d0.y], 1)] = s0.y;
    colsrc[atomicAdd(&cur[d0.z], 1)] = s0.z;
    colsrc[atomicAdd(&cur[d0.w], 1)] = s0.w;
    colsrc[atomicAdd(&cur[d1.x], 1)] = s1.x;
    colsrc[atomicAdd(&cur[d1.y], 1)] = s1.y;
    colsrc[atomicAdd(&cur[d1.z], 1)] = s1.z;
    colsrc[atomicAdd(&cur[d1.w], 1)] = s1.w;
  } else {
    for (int e = e0; e < NEDGE; ++e)
      colsrc[atomicAdd(&cur[dst[e]], 1)] = src[e];
  }
}

// ---------------------------------------------------------------------------
// gather1: 8 lanes/node; lane bit0 = d (8-dim half, 16B request),
// bits1-2 = p (4-way edge interleave). 2 requests/edge (was 4).
// fp32 accum; fused mean+xr1+b1+ELU -> h (fp32) and hb (bf16 table).
// ---------------------------------------------------------------------------
__global__ __launch_bounds__(256) void gather1_kernel(
    const int* __restrict__ rowptr, const int* __restrict__ colsrc,
    const uint4* __restrict__ valb8, const float4* __restrict__ xr14,
    const float* __restrict__ b1, float4* __restrict__ h4,
    uint4* __restrict__ hb8) {
  int t = blockIdx.x * 256 + threadIdx.x;
  int n = t >> 3;
  if (n >= N_NODES) return;
  int d = t & 1;
  int p = (t >> 1) & 3;
  int beg = rowptr[n], end = rowptr[n + 1];

  float a[8] = {0.f, 0.f, 0.f, 0.f, 0.f, 0.f, 0.f, 0.f};
  int bA = (beg + 3) & ~3;
  int eA = end & ~3;
  if (bA > eA) {
    if (p == 0)
      for (int j = beg; j < end; ++j) accum8(valb8[colsrc[j] * 2 + d], a);
  } else {
    if (p == 0) {
      for (int j = beg; j < bA; ++j) accum8(valb8[colsrc[j] * 2 + d], a);
    } else if (p == 3) {
      for (int j = eA; j < end; ++j) accum8(valb8[colsrc[j] * 2 + d], a);
    }
    float a1[8] = {0.f, 0.f, 0.f, 0.f, 0.f, 0.f, 0.f, 0.f};
    int j = bA + p * 4;
    for (; j + 20 <= eA; j += 32) {
      v4i c0 = __builtin_nontemporal_load((const v4i*)(colsrc + j));
      v4i c1 = __builtin_nontemporal_load((const v4i*)(colsrc + j + 16));
      uint4 w0 = valb8[c0.x * 2 + d];
      uint4 w1 = valb8[c0.y * 2 + d];
      uint4 w2 = valb8[c0.z * 2 + d];
      uint4 w3 = valb8[c0.w * 2 + d];
      uint4 w4 = valb8[c1.x * 2 + d];
      uint4 w5 = valb8[c1.y * 2 + d];
      uint4 w6 = valb8[c1.z * 2 + d];
      uint4 w7 = valb8[c1.w * 2 + d];
      accum8(w0, a);
      accum8(w1, a1);
      accum8(w2, a);
      accum8(w3, a1);
      accum8(w4, a);
      accum8(w5, a1);
      accum8(w6, a);
      accum8(w7, a1);
    }
    for (; j + 4 <= eA; j += 16) {
      v4i c0 = __builtin_nontemporal_load((const v4i*)(colsrc + j));
      accum8(valb8[c0.x * 2 + d], a);
      accum8(valb8[c0.y * 2 + d], a1);
      accum8(valb8[c0.z * 2 + d], a);
      accum8(valb8[c0.w * 2 + d], a1);
    }
#pragma unroll
    for (int k = 0; k < 8; ++k) a[k] += a1[k];
  }

  // reduce over the 4 edge-interleave lanes (bits 1-2)
#pragma unroll
  for (int k = 0; k < 8; ++k) {
    a[k] += __shfl_xor(a[k], 2);
    a[k] += __shfl_xor(a[k], 4);
  }
  if (p) return;

  float inv = 1.0f / fmaxf((float)(end - beg), 1.0f);
  float4 r0 = xr14[n * 4 + 2 * d];
  float4 r1 = xr14[n * 4 + 2 * d + 1];
  const float4* bb = (const float4*)b1;
  float4 bb0 = bb[2 * d], bb1 = bb[2 * d + 1];
  float o[8];
  o[0] = a[0] * inv + r0.x + bb0.x;
  o[1] = a[1] * inv + r0.y + bb0.y;
  o[2] = a[2] * inv + r0.z + bb0.z;
  o[3] = a[3] * inv + r0.w + bb0.w;
  o[4] = a[4] * inv + r1.x + bb1.x;
  o[5] = a[5] * inv + r1.y + bb1.y;
  o[6] = a[6] * inv + r1.z + bb1.z;
  o[7] = a[7] * inv + r1.w + bb1.w;
#pragma unroll
  for (int k = 0; k < 8; ++k) o[k] = (o[k] > 0.f) ? o[k] : expm1f(o[k]);
  h4[n * 4 + 2 * d] = make_float4(o[0], o[1], o[2], o[3]);
  h4[n * 4 + 2 * d + 1] = make_float4(o[4], o[5], o[6], o[7]);
  uint4 pk;
  pk.x = (unsigned)f2b(o[0]) | ((unsigned)f2b(o[1]) << 16);
  pk.y = (unsigned)f2b(o[2]) | ((unsigned)f2b(o[3]) << 16);
  pk.z = (unsigned)f2b(o[4]) | ((unsigned)f2b(o[5]) << 16);
  pk.w = (unsigned)f2b(o[6]) | ((unsigned)f2b(o[7]) << 16);
  hb8[n * 2 + d] = pk;
}

// ---------------------------------------------------------------------------
// gather2: same 16B-request structure over hb; writes mean agg2n (fp32).
// ---------------------------------------------------------------------------
__global__ __launch_bounds__(256) void gather2_kernel(
    const int* __restrict__ rowptr, const int* __restrict__ colsrc,
    const uint4* __restrict__ valb8, float4* __restrict__ agg2n4) {
  int t = blockIdx.x * 256 + threadIdx.x;
  int n = t >> 3;
  if (n >= N_NODES) return;
  int d = t & 1;
  int p = (t >> 1) & 3;
  int beg = rowptr[n], end = rowptr[n + 1];

  float a[8] = {0.f, 0.f, 0.f, 0.f, 0.f, 0.f, 0.f, 0.f};
  int bA = (beg + 3) & ~3;
  int eA = end & ~3;
  if (bA > eA) {
    if (p == 0)
      for (int j = beg; j < end; ++j) accum8(valb8[colsrc[j] * 2 + d], a);
  } else {
    if (p == 0) {
      for (int j = beg; j < bA; ++j) accum8(valb8[colsrc[j] * 2 + d], a);
    } else if (p == 3) {
      for (int j = eA; j < end; ++j) accum8(valb8[colsrc[j] * 2 + d], a);
    }
    float a1[8] = {0.f, 0.f, 0.f, 0.f, 0.f, 0.f, 0.f, 0.f};
    int j = bA + p * 4;
    for (; j + 20 <= eA; j += 32) {
      v4i c0 = __builtin_nontemporal_load((const v4i*)(colsrc + j));
      v4i c1 = __builtin_nontemporal_load((const v4i*)(colsrc + j + 16));
      uint4 w0 = valb8[c0.x * 2 + d];
      uint4 w1 = valb8[c0.y * 2 + d];
      uint4 w2 = valb8[c0.z * 2 + d];
      uint4 w3 = valb8[c0.w * 2 + d];
      uint4 w4 = valb8[c1.x * 2 + d];
      uint4 w5 = valb8[c1.y * 2 + d];
      uint4 w6 = valb8[c1.z * 2 + d];
      uint4 w7 = valb8[c1.w * 2 + d];
      accum8(w0, a);
      accum8(w1, a1);
      accum8(w2, a);
      accum8(w3, a1);
      accum8(w4, a);
      accum8(w5, a1);
      accum8(w6, a);
      accum8(w7, a1);
    }
    for (; j + 4 <= eA; j += 16) {
      v4i c0 = __builtin_nontemporal_load((const v4i*)(colsrc + j));
      accum8(valb8[c0.x * 2 + d], a);
      accum8(valb8[c0.y * 2 + d], a1);
      accum8(valb8[c0.z * 2 + d], a);
      accum8(valb8[c0.w * 2 + d], a1);
    }
#pragma unroll
    for (int k = 0; k < 8; ++k) a[k] += a1[k];
  }

#pragma unroll
  for (int k = 0; k < 8; ++k) {
    a[k] += __shfl_xor(a[k], 2);
    a[k] += __shfl_xor(a[k], 4);
  }
  if (p) return;

  float inv = 1.0f / fmaxf((float)(end - beg), 1.0f);
  agg2n4[n * 4 + 2 * d] =
      make_float4(a[0] * inv, a[1] * inv, a[2] * inv, a[3] * inv);
  agg2n4[n * 4 + 2 * d + 1] =
      make_float4(a[4] * inv, a[5] * inv, a[6] * inv, a[7] * inv);
}

// ---------------------------------------------------------------------------
// out: agg2n @ W2[1] + h @ root2 + b2, log_softmax, fp32 store. (unchanged)
// ---------------------------------------------------------------------------
__global__ __launch_bounds__(256) void out_kernel(
    const float* __restrict__ h, const float* __restrict__ agg2n,
    const float* __restrict__ W2, const float* __restrict__ root2,
    const float* __restrict__ b2v, float* __restrict__ out) {
  __shared__ float Wl[HID * NCLS];
  __shared__ float Rl[HID * NCLS];
  __shared__ float Bl[NCLS];
  for (int i = threadIdx.x; i < HID * NCLS; i += blockDim.x) {
    Wl[i] = W2[HID * NCLS + i];
    Rl[i] = root2[i];
  }
  if (threadIdx.x < NCLS) Bl[threadIdx.x] = b2v[threadIdx.x];
  __syncthreads();

  int n = blockIdx.x * blockDim.x + threadIdx.x;
  if (n >= N_NODES) return;

  float hv[HID], av[HID];
#pragma unroll
  for (int c = 0; c < HID; ++c) {
    hv[c] = h[n * HID + c];
    av[c] = agg2n[n * HID + c];
  }
  float logit[NCLS];
#pragma unroll
  for (int j = 0; j < NCLS; ++j) logit[j] = Bl[j];
  for (int c = 0; c < HID; ++c) {
    float hc = hv[c], ac = av[c];
#pragma unroll
    for (int j = 0; j < NCLS; ++j)
      logit[j] += ac * Wl[c * NCLS + j] + hc * Rl[c * NCLS + j];
  }
  float m = -INFINITY;
#pragma unroll
  for (int j = 0; j < NCLS; ++j) m = fmaxf(m, logit[j]);
  float s = 0.f;
#pragma unroll
  for (int j = 0; j < NCLS; ++j) s += expf(logit[j] - m);
  float lse = m + logf(s);
#pragma unroll
  for (int j = 0; j < NCLS; ++j)
    out[(size_t)n * NCLS + j] = logit[j] - lse;
}

extern "C" void kernel_launch(void* const* d_in, const int* in_sizes, int n_in,
                              void* d_out, int out_size, void* d_ws,
                              size_t ws_size, hipStream_t stream) {
  const float* x = (const float*)d_in[0];
  const int* ei = (const int*)d_in[1];  // (2, E): src row then dst row
  const float* W1 = (const float*)d_in[2];
  const float* root1 = (const float*)d_in[3];
  const float* b1 = (const float*)d_in[4];
  const float* W2 = (const float*)d_in[5];
  const float* root2 = (const float*)d_in[6];
  const float* b2v = (const float*)d_in[7];
  float* out = (float*)d_out;

  const int* src = ei;
  const int* dstp = ei + NEDGE;

  // workspace (bytes), ~40 MB:
  // [rowptr (N+1) pad][cur N (also deg)][bsum 2K][boff 2K][colsrc E*4]
  // [xw1b 16N*2][xr1 16N*4][hb 16N*2][h 16N*4][agg2n 16N*4]
  char* w = (char*)d_ws;
  int* rowptr = (int*)w;   w += 400128;                    // (N+1)*4 padded
  int* cur = (int*)w;      w += (size_t)N_NODES * 4;       // deg, then cursors
  int* bsum = (int*)w;     w += 2048;
  int* boff = (int*)w;     w += 2048;
  int* colsrc = (int*)w;   w += (size_t)NEDGE * 4;
  unsigned* xw1b = (unsigned*)w;           w += (size_t)N_NODES * HID * 2;
  float* xr1 = (float*)w;                  w += (size_t)N_NODES * HID * 4;
  unsigned short* hb = (unsigned short*)w; w += (size_t)N_NODES * HID * 2;
  float* h = (float*)w;                    w += (size_t)N_NODES * HID * 4;
  float* agg2n = (float*)w;                w += (size_t)N_NODES * HID * 4;

  hipMemsetAsync(cur, 0, (size_t)N_NODES * 4, stream);

  proj1_kernel<<<(N_NODES + 63) / 64, 256, 0, stream>>>(x, W1, root1, xw1b,
                                                        xr1);
  deg_kernel<<<NCHUNK, 512, 0, stream>>>(dstp, cur);
  scanB_kernel<<<NBUCK, 256, 0, stream>>>(cur, rowptr, bsum);
  scanS_kernel<<<1, 512, 0, stream>>>(bsum, boff, rowptr);
  fix_kernel<<<NBUCK, 256, 0, stream>>>(boff, rowptr, cur);
  scatter_kernel<<<NCHUNK, 512, 0, stream>>>(src, dstp, cur, colsrc);
  gather1_kernel<<<(N_NODES * 8 + 255) / 256, 256, 0, stream>>>(
      rowptr, colsrc, (const uint4*)xw1b, (const float4*)xr1, b1, (float4*)h,
      (uint4*)hb);
  gather2_kernel<<<(N_NODES * 8 + 255) / 256, 256, 0, stream>>>(
      rowptr, colsrc, (const uint4*)hb, (float4*)agg2n);
  out_kernel<<<NBUCK, 256, 0, stream>>>(h, agg2n, W2, root2, b2v, out);
}

// Round 7
// 291.928 us; speedup vs baseline: 2.1426x; 2.1426x over previous
//
#include <hip/hip_runtime.h>
#include <hip/hip_bf16.h>

#define N_NODES 100000
#define FIN 128
#define HID 16
#define NCLS 40
#define NEDGE 3200000
#define NBUCK 391     // ceil(100000/256): 256 dst-nodes per bucket
#define NCHUNK 782    // ceil(NEDGE/4096)
#define W_ROW 144     // swizzled W row stride (floats)

typedef int v4i __attribute__((ext_vector_type(4)));

// f32 -> bf16 (RNE)
__device__ __forceinline__ unsigned short f2b(float f) {
  union { float f; unsigned u; } v;
  v.f = f;
  unsigned r = v.u + 0x7FFFu + ((v.u >> 16) & 1u);
  return (unsigned short)(r >> 16);
}

// accumulate 8 bf16 (one uint4 = 16B) into 8 fp32
__device__ __forceinline__ void accum8(uint4 w, float* a) {
  union { unsigned u; float f; } t;
  t.u = w.x << 16;         a[0] += t.f;
  t.u = w.x & 0xFFFF0000u; a[1] += t.f;
  t.u = w.y << 16;         a[2] += t.f;
  t.u = w.y & 0xFFFF0000u; a[3] += t.f;
  t.u = w.z << 16;         a[4] += t.f;
  t.u = w.z & 0xFFFF0000u; a[5] += t.f;
  t.u = w.w << 16;         a[6] += t.f;
  t.u = w.w & 0xFFFF0000u; a[7] += t.f;
}

// ---------------------------------------------------------------------------
// proj1: 4 lanes per node, W in bank-swizzled LDS, shfl butterfly.
// ---------------------------------------------------------------------------
__global__ __launch_bounds__(256) void proj1_kernel(
    const float* __restrict__ x, const float* __restrict__ W1,
    const float* __restrict__ root1,
    unsigned* __restrict__ xw1b, float* __restrict__ xr1) {
  __shared__ float Wl[32 * W_ROW];  // 18.4 KB

  int tid = threadIdx.x;
  for (int t = tid; t < 32 * FIN; t += 256) {
    int c = t >> 7, k = t & 127;
    float v = (c < 16) ? W1[FIN * HID + k * HID + c] : root1[k * HID + (c - 16)];
    Wl[c * W_ROW + k + ((k >> 5) << 2)] = v;
  }
  __syncthreads();

  int n = blockIdx.x * 64 + (tid >> 2);
  int j = tid & 3;
  bool live = (n < N_NODES);

  float4 xv[8];
  if (live) {
    const float4* xr = (const float4*)(x + (size_t)n * FIN + j * 32);
#pragma unroll
    for (int m = 0; m < 8; ++m) xv[m] = xr[m];
  } else {
#pragma unroll
    for (int m = 0; m < 8; ++m) xv[m] = make_float4(0.f, 0.f, 0.f, 0.f);
  }

  float acc[32];
  const float* wj = Wl + j * 36;
#pragma unroll 4
  for (int c = 0; c < 32; ++c) {
    const float4* wr = (const float4*)(wj + c * W_ROW);
    float s = 0.f;
#pragma unroll
    for (int m = 0; m < 8; ++m) {
      float4 wv = wr[m];
      s += xv[m].x * wv.x + xv[m].y * wv.y + xv[m].z * wv.z + xv[m].w * wv.w;
    }
    acc[c] = s;
  }

#pragma unroll
  for (int c = 0; c < 32; ++c) {
    acc[c] += __shfl_xor(acc[c], 1);
    acc[c] += __shfl_xor(acc[c], 2);
  }
  if (!live) return;

  if (j == 0) {
    uint4 pk;
    pk.x = (unsigned)f2b(acc[0]) | ((unsigned)f2b(acc[1]) << 16);
    pk.y = (unsigned)f2b(acc[2]) | ((unsigned)f2b(acc[3]) << 16);
    pk.z = (unsigned)f2b(acc[4]) | ((unsigned)f2b(acc[5]) << 16);
    pk.w = (unsigned)f2b(acc[6]) | ((unsigned)f2b(acc[7]) << 16);
    *(uint4*)((char*)xw1b + (size_t)n * 32) = pk;
  } else if (j == 1) {
    uint4 pk;
    pk.x = (unsigned)f2b(acc[8]) | ((unsigned)f2b(acc[9]) << 16);
    pk.y = (unsigned)f2b(acc[10]) | ((unsigned)f2b(acc[11]) << 16);
    pk.z = (unsigned)f2b(acc[12]) | ((unsigned)f2b(acc[13]) << 16);
    pk.w = (unsigned)f2b(acc[14]) | ((unsigned)f2b(acc[15]) << 16);
    *(uint4*)((char*)xw1b + (size_t)n * 32 + 16) = pk;
  } else if (j == 2) {
    *(float4*)(xr1 + (size_t)n * 16 + 0) =
        make_float4(acc[16], acc[17], acc[18], acc[19]);
    *(float4*)(xr1 + (size_t)n * 16 + 4) =
        make_float4(acc[20], acc[21], acc[22], acc[23]);
  } else {
    *(float4*)(xr1 + (size_t)n * 16 + 8) =
        make_float4(acc[24], acc[25], acc[26], acc[27]);
    *(float4*)(xr1 + (size_t)n * 16 + 12) =
        make_float4(acc[28], acc[29], acc[30], acc[31]);
  }
}

// ---------------------------------------------------------------------------
// histB: bucket histogram (391 counters), LDS pre-aggregation. 512 threads.
// ---------------------------------------------------------------------------
__global__ __launch_bounds__(512) void histB_kernel(
    const int* __restrict__ dst, int* __restrict__ bcnt) {
  __shared__ int hc[NBUCK];
  for (int t = threadIdx.x; t < NBUCK; t += 512) hc[t] = 0;
  __syncthreads();
  int base = blockIdx.x * 4096;
#pragma unroll
  for (int k = 0; k < 8; ++k) {
    int e = base + k * 512 + threadIdx.x;
    if (e < NEDGE) atomicAdd(&hc[dst[e] >> 8], 1);
  }
  __syncthreads();
  for (int t = threadIdx.x; t < NBUCK; t += 512) {
    int v = hc[t];
    if (v) atomicAdd(&bcnt[t], v);
  }
}

// ---------------------------------------------------------------------------
// scan: exclusive scan of 391 counts -> boff, gcursor; set sentinels.
// ---------------------------------------------------------------------------
__global__ __launch_bounds__(512) void scan_kernel(
    const int* __restrict__ bcnt, int* __restrict__ boff,
    int* __restrict__ gcursor, int* __restrict__ rowptr) {
  __shared__ int s[512];
  int v = (threadIdx.x < NBUCK) ? bcnt[threadIdx.x] : 0;
  s[threadIdx.x] = v;
  __syncthreads();
  for (int off = 1; off < 512; off <<= 1) {
    int t = (threadIdx.x >= off) ? s[threadIdx.x - off] : 0;
    __syncthreads();
    s[threadIdx.x] += t;
    __syncthreads();
  }
  if (threadIdx.x < NBUCK) {
    int e = s[threadIdx.x] - v;
    boff[threadIdx.x] = e;
    gcursor[threadIdx.x] = e;
  }
  if (threadIdx.x == 0) {
    boff[NBUCK] = NEDGE;
    rowptr[N_NODES] = NEDGE;
  }
}

// ---------------------------------------------------------------------------
// partA: multi-split partition, 4096-edge chunks, 512 threads.
// rec = src | (dst&255)<<17. LDS rank atomics; run-contiguous global writes.
// ---------------------------------------------------------------------------
__global__ __launch_bounds__(512) void partA_kernel(
    const int* __restrict__ src, const int* __restrict__ dst,
    int* __restrict__ gcursor, unsigned* __restrict__ recs) {
  __shared__ int cnt[NBUCK];
  __shared__ int base[NBUCK];
  for (int t = threadIdx.x; t < NBUCK; t += 512) cnt[t] = 0;
  __syncthreads();

  int ebase = blockIdx.x * 4096;
  unsigned recv[8];
  int bk[8];
  int rank[8];
#pragma unroll
  for (int k = 0; k < 8; ++k) {
    int e = ebase + k * 512 + threadIdx.x;
    if (e < NEDGE) {
      int d = dst[e];
      bk[k] = d >> 8;
      recv[k] = (unsigned)src[e] | ((unsigned)(d & 255) << 17);
      rank[k] = atomicAdd(&cnt[bk[k]], 1);
    } else {
      bk[k] = -1;
    }
  }
  __syncthreads();
  for (int t = threadIdx.x; t < NBUCK; t += 512) {
    int cv = cnt[t];
    base[t] = cv ? atomicAdd(&gcursor[t], cv) : 0;
  }
  __syncthreads();
#pragma unroll
  for (int k = 0; k < 8; ++k)
    if (bk[k] >= 0) recs[base[bk[k]] + rank[k]] = recv[k];
}

// ---------------------------------------------------------------------------
// sortB: per-bucket counting sort -> dst-sorted CSR. 1024 threads.
// ---------------------------------------------------------------------------
__global__ __launch_bounds__(1024) void sortB_kernel(
    const int* __restrict__ boff, const unsigned* __restrict__ recs,
    int* __restrict__ rowptr, int* __restrict__ colsrc) {
  __shared__ int hist[256];
  __shared__ int s[256];
  __shared__ int cur[256];
  if (threadIdx.x < 256) hist[threadIdx.x] = 0;
  __syncthreads();

  int b = blockIdx.x;
  int beg = boff[b], end = boff[b + 1];
  for (int j = beg + threadIdx.x; j < end; j += 1024)
    atomicAdd(&hist[recs[j] >> 17], 1);
  __syncthreads();

  if (threadIdx.x < 256) s[threadIdx.x] = hist[threadIdx.x];
  __syncthreads();
  for (int off = 1; off < 256; off <<= 1) {
    int t = 0;
    if (threadIdx.x < 256 && threadIdx.x >= off) t = s[threadIdx.x - off];
    __syncthreads();
    if (threadIdx.x < 256) s[threadIdx.x] += t;
    __syncthreads();
  }
  if (threadIdx.x < 256) {
    int excl = s[threadIdx.x] - hist[threadIdx.x];
    int n = b * 256 + threadIdx.x;
    if (n < N_NODES) rowptr[n] = beg + excl;
    cur[threadIdx.x] = excl;
  }
  __syncthreads();

  for (int j = beg + threadIdx.x; j < end; j += 1024) {
    unsigned r = recs[j];
    int dl = r >> 17;
    int pos = atomicAdd(&cur[dl], 1);
    colsrc[beg + pos] = (int)(r & 0x1FFFF);
  }
}

// ---------------------------------------------------------------------------
// gather1: 8 lanes/node; lane bit0 = d (8-dim half, 16B request),
// bits1-2 = p (4-way edge interleave). 2 requests/edge (was 4x8B in R4).
// fp32 accum; fused mean+xr1+b1+ELU -> h (fp32) and hb (bf16 table).
// ---------------------------------------------------------------------------
__global__ __launch_bounds__(256) void gather1_kernel(
    const int* __restrict__ rowptr, const int* __restrict__ colsrc,
    const uint4* __restrict__ valb8, const float4* __restrict__ xr14,
    const float* __restrict__ b1, float4* __restrict__ h4,
    uint4* __restrict__ hb8) {
  int t = blockIdx.x * 256 + threadIdx.x;
  int n = t >> 3;
  if (n >= N_NODES) return;
  int d = t & 1;
  int p = (t >> 1) & 3;
  int beg = rowptr[n], end = rowptr[n + 1];

  float a[8] = {0.f, 0.f, 0.f, 0.f, 0.f, 0.f, 0.f, 0.f};
  int bA = (beg + 3) & ~3;
  int eA = end & ~3;
  if (bA > eA) {
    if (p == 0)
      for (int j = beg; j < end; ++j) accum8(valb8[colsrc[j] * 2 + d], a);
  } else {
    if (p == 0) {
      for (int j = beg; j < bA; ++j) accum8(valb8[colsrc[j] * 2 + d], a);
    } else if (p == 3) {
      for (int j = eA; j < end; ++j) accum8(valb8[colsrc[j] * 2 + d], a);
    }
    float a1[8] = {0.f, 0.f, 0.f, 0.f, 0.f, 0.f, 0.f, 0.f};
    int j = bA + p * 4;
    for (; j + 20 <= eA; j += 32) {
      v4i c0 = __builtin_nontemporal_load((const v4i*)(colsrc + j));
      v4i c1 = __builtin_nontemporal_load((const v4i*)(colsrc + j + 16));
      uint4 w0 = valb8[c0.x * 2 + d];
      uint4 w1 = valb8[c0.y * 2 + d];
      uint4 w2 = valb8[c0.z * 2 + d];
      uint4 w3 = valb8[c0.w * 2 + d];
      uint4 w4 = valb8[c1.x * 2 + d];
      uint4 w5 = valb8[c1.y * 2 + d];
      uint4 w6 = valb8[c1.z * 2 + d];
      uint4 w7 = valb8[c1.w * 2 + d];
      accum8(w0, a);
      accum8(w1, a1);
      accum8(w2, a);
      accum8(w3, a1);
      accum8(w4, a);
      accum8(w5, a1);
      accum8(w6, a);
      accum8(w7, a1);
    }
    for (; j + 4 <= eA; j += 16) {
      v4i c0 = __builtin_nontemporal_load((const v4i*)(colsrc + j));
      accum8(valb8[c0.x * 2 + d], a);
      accum8(valb8[c0.y * 2 + d], a1);
      accum8(valb8[c0.z * 2 + d], a);
      accum8(valb8[c0.w * 2 + d], a1);
    }
#pragma unroll
    for (int k = 0; k < 8; ++k) a[k] += a1[k];
  }

  // reduce over the 4 edge-interleave lanes (bits 1-2)
#pragma unroll
  for (int k = 0; k < 8; ++k) {
    a[k] += __shfl_xor(a[k], 2);
    a[k] += __shfl_xor(a[k], 4);
  }
  if (p) return;

  float inv = 1.0f / fmaxf((float)(end - beg), 1.0f);
  float4 r0 = xr14[n * 4 + 2 * d];
  float4 r1 = xr14[n * 4 + 2 * d + 1];
  const float4* bb = (const float4*)b1;
  float4 bb0 = bb[2 * d], bb1 = bb[2 * d + 1];
  float o[8];
  o[0] = a[0] * inv + r0.x + bb0.x;
  o[1] = a[1] * inv + r0.y + bb0.y;
  o[2] = a[2] * inv + r0.z + bb0.z;
  o[3] = a[3] * inv + r0.w + bb0.w;
  o[4] = a[4] * inv + r1.x + bb1.x;
  o[5] = a[5] * inv + r1.y + bb1.y;
  o[6] = a[6] * inv + r1.z + bb1.z;
  o[7] = a[7] * inv + r1.w + bb1.w;
#pragma unroll
  for (int k = 0; k < 8; ++k) o[k] = (o[k] > 0.f) ? o[k] : expm1f(o[k]);
  h4[n * 4 + 2 * d] = make_float4(o[0], o[1], o[2], o[3]);
  h4[n * 4 + 2 * d + 1] = make_float4(o[4], o[5], o[6], o[7]);
  uint4 pk;
  pk.x = (unsigned)f2b(o[0]) | ((unsigned)f2b(o[1]) << 16);
  pk.y = (unsigned)f2b(o[2]) | ((unsigned)f2b(o[3]) << 16);
  pk.z = (unsigned)f2b(o[4]) | ((unsigned)f2b(o[5]) << 16);
  pk.w = (unsigned)f2b(o[6]) | ((unsigned)f2b(o[7]) << 16);
  hb8[n * 2 + d] = pk;
}

// ---------------------------------------------------------------------------
// gather2: same 16B-request structure over hb; writes mean agg2n (fp32).
// ---------------------------------------------------------------------------
__global__ __launch_bounds__(256) void gather2_kernel(
    const int* __restrict__ rowptr, const int* __restrict__ colsrc,
    const uint4* __restrict__ valb8, float4* __restrict__ agg2n4) {
  int t = blockIdx.x * 256 + threadIdx.x;
  int n = t >> 3;
  if (n >= N_NODES) return;
  int d = t & 1;
  int p = (t >> 1) & 3;
  int beg = rowptr[n], end = rowptr[n + 1];

  float a[8] = {0.f, 0.f, 0.f, 0.f, 0.f, 0.f, 0.f, 0.f};
  int bA = (beg + 3) & ~3;
  int eA = end & ~3;
  if (bA > eA) {
    if (p == 0)
      for (int j = beg; j < end; ++j) accum8(valb8[colsrc[j] * 2 + d], a);
  } else {
    if (p == 0) {
      for (int j = beg; j < bA; ++j) accum8(valb8[colsrc[j] * 2 + d], a);
    } else if (p == 3) {
      for (int j = eA; j < end; ++j) accum8(valb8[colsrc[j] * 2 + d], a);
    }
    float a1[8] = {0.f, 0.f, 0.f, 0.f, 0.f, 0.f, 0.f, 0.f};
    int j = bA + p * 4;
    for (; j + 20 <= eA; j += 32) {
      v4i c0 = __builtin_nontemporal_load((const v4i*)(colsrc + j));
      v4i c1 = __builtin_nontemporal_load((const v4i*)(colsrc + j + 16));
      uint4 w0 = valb8[c0.x * 2 + d];
      uint4 w1 = valb8[c0.y * 2 + d];
      uint4 w2 = valb8[c0.z * 2 + d];
      uint4 w3 = valb8[c0.w * 2 + d];
      uint4 w4 = valb8[c1.x * 2 + d];
      uint4 w5 = valb8[c1.y * 2 + d];
      uint4 w6 = valb8[c1.z * 2 + d];
      uint4 w7 = valb8[c1.w * 2 + d];
      accum8(w0, a);
      accum8(w1, a1);
      accum8(w2, a);
      accum8(w3, a1);
      accum8(w4, a);
      accum8(w5, a1);
      accum8(w6, a);
      accum8(w7, a1);
    }
    for (; j + 4 <= eA; j += 16) {
      v4i c0 = __builtin_nontemporal_load((const v4i*)(colsrc + j));
      accum8(valb8[c0.x * 2 + d], a);
      accum8(valb8[c0.y * 2 + d], a1);
      accum8(valb8[c0.z * 2 + d], a);
      accum8(valb8[c0.w * 2 + d], a1);
    }
#pragma unroll
    for (int k = 0; k < 8; ++k) a[k] += a1[k];
  }

#pragma unroll
  for (int k = 0; k < 8; ++k) {
    a[k] += __shfl_xor(a[k], 2);
    a[k] += __shfl_xor(a[k], 4);
  }
  if (p) return;

  float inv = 1.0f / fmaxf((float)(end - beg), 1.0f);
  agg2n4[n * 4 + 2 * d] =
      make_float4(a[0] * inv, a[1] * inv, a[2] * inv, a[3] * inv);
  agg2n4[n * 4 + 2 * d + 1] =
      make_float4(a[4] * inv, a[5] * inv, a[6] * inv, a[7] * inv);
}

// ---------------------------------------------------------------------------
// out: agg2n @ W2[1] + h @ root2 + b2, log_softmax, fp32 store.
// ---------------------------------------------------------------------------
__global__ __launch_bounds__(256) void out_kernel(
    const float* __restrict__ h, const float* __restrict__ agg2n,
    const float* __restrict__ W2, const float* __restrict__ root2,
    const float* __restrict__ b2v, float* __restrict__ out) {
  __shared__ float Wl[HID * NCLS];
  __shared__ float Rl[HID * NCLS];
  __shared__ float Bl[NCLS];
  for (int i = threadIdx.x; i < HID * NCLS; i += blockDim.x) {
    Wl[i] = W2[HID * NCLS + i];
    Rl[i] = root2[i];
  }
  if (threadIdx.x < NCLS) Bl[threadIdx.x] = b2v[threadIdx.x];
  __syncthreads();

  int n = blockIdx.x * blockDim.x + threadIdx.x;
  if (n >= N_NODES) return;

  float hv[HID], av[HID];
#pragma unroll
  for (int c = 0; c < HID; ++c) {
    hv[c] = h[n * HID + c];
    av[c] = agg2n[n * HID + c];
  }
  float logit[NCLS];
#pragma unroll
  for (int j = 0; j < NCLS; ++j) logit[j] = Bl[j];
  for (int c = 0; c < HID; ++c) {
    float hc = hv[c], ac = av[c];
#pragma unroll
    for (int j = 0; j < NCLS; ++j)
      logit[j] += ac * Wl[c * NCLS + j] + hc * Rl[c * NCLS + j];
  }
  float m = -INFINITY;
#pragma unroll
  for (int j = 0; j < NCLS; ++j) m = fmaxf(m, logit[j]);
  float s = 0.f;
#pragma unroll
  for (int j = 0; j < NCLS; ++j) s += expf(logit[j] - m);
  float lse = m + logf(s);
#pragma unroll
  for (int j = 0; j < NCLS; ++j)
    out[(size_t)n * NCLS + j] = logit[j] - lse;
}

extern "C" void kernel_launch(void* const* d_in, const int* in_sizes, int n_in,
                              void* d_out, int out_size, void* d_ws,
                              size_t ws_size, hipStream_t stream) {
  const float* x = (const float*)d_in[0];
  const int* ei = (const int*)d_in[1];  // (2, E): src row then dst row
  const float* W1 = (const float*)d_in[2];
  const float* root1 = (const float*)d_in[3];
  const float* b1 = (const float*)d_in[4];
  const float* W2 = (const float*)d_in[5];
  const float* root2 = (const float*)d_in[6];
  const float* b2v = (const float*)d_in[7];
  float* out = (float*)d_out;

  const int* src = ei;
  const int* dstp = ei + NEDGE;

  // workspace (bytes):
  // [bcnt 2K][boff 2K][gcursor 2K][rowptr (N+4)*4]
  // [recs E*4  (lower half reused as h fp32, upper half as agg2n fp32)]
  // [colsrc E*4][xw1b 16N*2][xr1 16N*4][hb 16N*2]
  char* w = (char*)d_ws;
  int* bcnt = (int*)w;           w += 2048;
  int* boff = (int*)w;           w += 2048;
  int* gcursor = (int*)w;        w += 2048;
  int* rowptr = (int*)w;         w += (size_t)(N_NODES + 4) * 4;
  unsigned* recs = (unsigned*)w; w += (size_t)NEDGE * 4;
  int* colsrc = (int*)w;         w += (size_t)NEDGE * 4;
  unsigned* xw1b = (unsigned*)w; w += (size_t)N_NODES * HID * 2;
  float* xr1 = (float*)w;        w += (size_t)N_NODES * HID * 4;
  unsigned short* hb = (unsigned short*)w; w += (size_t)N_NODES * HID * 2;

  float* h = (float*)recs;  // recs dead after sortB; h = 6.4MB (half of recs)
  float* agg2n = (float*)((char*)recs + (size_t)N_NODES * HID * 4);

  hipMemsetAsync(bcnt, 0, 2048, stream);

  proj1_kernel<<<(N_NODES + 63) / 64, 256, 0, stream>>>(x, W1, root1, xw1b,
                                                        xr1);
  histB_kernel<<<NCHUNK, 512, 0, stream>>>(dstp, bcnt);
  scan_kernel<<<1, 512, 0, stream>>>(bcnt, boff, gcursor, rowptr);
  partA_kernel<<<NCHUNK, 512, 0, stream>>>(src, dstp, gcursor, recs);
  sortB_kernel<<<NBUCK, 1024, 0, stream>>>(boff, recs, rowptr, colsrc);
  gather1_kernel<<<(N_NODES * 8 + 255) / 256, 256, 0, stream>>>(
      rowptr, colsrc, (const uint4*)xw1b, (const float4*)xr1, b1, (float4*)h,
      (uint4*)hb);
  gather2_kernel<<<(N_NODES * 8 + 255) / 256, 256, 0, stream>>>(
      rowptr, colsrc, (const uint4*)hb, (float4*)agg2n);
  out_kernel<<<(N_NODES + 255) / 256, 256, 0, stream>>>(h, agg2n, W2, root2,
                                                        b2v, out);
}

// Round 8
// 273.423 us; speedup vs baseline: 2.2876x; 1.0677x over previous
//
#include <hip/hip_runtime.h>
#include <hip/hip_bf16.h>

#define N_NODES 100000
#define FIN 128
#define HID 16
#define NCLS 40
#define NEDGE 3200000
#define NBUCK 391     // ceil(100000/256): 256 dst-nodes per bucket
#define NCHUNK 782    // ceil(NEDGE/4096)
#define W_ROW 144     // swizzled W row stride (floats)
#define SCAP 12288    // sortB staged capacity (48KB); max bucket ~8.5K

typedef int v4i __attribute__((ext_vector_type(4)));

// f32 -> bf16 (RNE)
__device__ __forceinline__ unsigned short f2b(float f) {
  union { float f; unsigned u; } v;
  v.f = f;
  unsigned r = v.u + 0x7FFFu + ((v.u >> 16) & 1u);
  return (unsigned short)(r >> 16);
}

// accumulate 8 bf16 (one uint4 = 16B) into 8 fp32
__device__ __forceinline__ void accum8(uint4 w, float* a) {
  union { unsigned u; float f; } t;
  t.u = w.x << 16;         a[0] += t.f;
  t.u = w.x & 0xFFFF0000u; a[1] += t.f;
  t.u = w.y << 16;         a[2] += t.f;
  t.u = w.y & 0xFFFF0000u; a[3] += t.f;
  t.u = w.z << 16;         a[4] += t.f;
  t.u = w.z & 0xFFFF0000u; a[5] += t.f;
  t.u = w.w << 16;         a[6] += t.f;
  t.u = w.w & 0xFFFF0000u; a[7] += t.f;
}

// ---------------------------------------------------------------------------
// proj1: 4 lanes per node, W in bank-swizzled LDS, shfl butterfly. (unchanged)
// ---------------------------------------------------------------------------
__global__ __launch_bounds__(256) void proj1_kernel(
    const float* __restrict__ x, const float* __restrict__ W1,
    const float* __restrict__ root1,
    unsigned* __restrict__ xw1b, float* __restrict__ xr1) {
  __shared__ float Wl[32 * W_ROW];  // 18.4 KB

  int tid = threadIdx.x;
  for (int t = tid; t < 32 * FIN; t += 256) {
    int c = t >> 7, k = t & 127;
    float v = (c < 16) ? W1[FIN * HID + k * HID + c] : root1[k * HID + (c - 16)];
    Wl[c * W_ROW + k + ((k >> 5) << 2)] = v;
  }
  __syncthreads();

  int n = blockIdx.x * 64 + (tid >> 2);
  int j = tid & 3;
  bool live = (n < N_NODES);

  float4 xv[8];
  if (live) {
    const float4* xr = (const float4*)(x + (size_t)n * FIN + j * 32);
#pragma unroll
    for (int m = 0; m < 8; ++m) xv[m] = xr[m];
  } else {
#pragma unroll
    for (int m = 0; m < 8; ++m) xv[m] = make_float4(0.f, 0.f, 0.f, 0.f);
  }

  float acc[32];
  const float* wj = Wl + j * 36;
#pragma unroll 4
  for (int c = 0; c < 32; ++c) {
    const float4* wr = (const float4*)(wj + c * W_ROW);
    float s = 0.f;
#pragma unroll
    for (int m = 0; m < 8; ++m) {
      float4 wv = wr[m];
      s += xv[m].x * wv.x + xv[m].y * wv.y + xv[m].z * wv.z + xv[m].w * wv.w;
    }
    acc[c] = s;
  }

#pragma unroll
  for (int c = 0; c < 32; ++c) {
    acc[c] += __shfl_xor(acc[c], 1);
    acc[c] += __shfl_xor(acc[c], 2);
  }
  if (!live) return;

  if (j == 0) {
    uint4 pk;
    pk.x = (unsigned)f2b(acc[0]) | ((unsigned)f2b(acc[1]) << 16);
    pk.y = (unsigned)f2b(acc[2]) | ((unsigned)f2b(acc[3]) << 16);
    pk.z = (unsigned)f2b(acc[4]) | ((unsigned)f2b(acc[5]) << 16);
    pk.w = (unsigned)f2b(acc[6]) | ((unsigned)f2b(acc[7]) << 16);
    *(uint4*)((char*)xw1b + (size_t)n * 32) = pk;
  } else if (j == 1) {
    uint4 pk;
    pk.x = (unsigned)f2b(acc[8]) | ((unsigned)f2b(acc[9]) << 16);
    pk.y = (unsigned)f2b(acc[10]) | ((unsigned)f2b(acc[11]) << 16);
    pk.z = (unsigned)f2b(acc[12]) | ((unsigned)f2b(acc[13]) << 16);
    pk.w = (unsigned)f2b(acc[14]) | ((unsigned)f2b(acc[15]) << 16);
    *(uint4*)((char*)xw1b + (size_t)n * 32 + 16) = pk;
  } else if (j == 2) {
    *(float4*)(xr1 + (size_t)n * 16 + 0) =
        make_float4(acc[16], acc[17], acc[18], acc[19]);
    *(float4*)(xr1 + (size_t)n * 16 + 4) =
        make_float4(acc[20], acc[21], acc[22], acc[23]);
  } else {
    *(float4*)(xr1 + (size_t)n * 16 + 8) =
        make_float4(acc[24], acc[25], acc[26], acc[27]);
    *(float4*)(xr1 + (size_t)n * 16 + 12) =
        make_float4(acc[28], acc[29], acc[30], acc[31]);
  }
}

// ---------------------------------------------------------------------------
// histB: bucket histogram, LDS pre-aggregation, int4-vectorized dst reads.
// ---------------------------------------------------------------------------
__global__ __launch_bounds__(512) void histB_kernel(
    const int* __restrict__ dst, int* __restrict__ bcnt) {
  __shared__ int hc[NBUCK];
  for (int t = threadIdx.x; t < NBUCK; t += 512) hc[t] = 0;
  __syncthreads();
  int e0 = blockIdx.x * 4096 + threadIdx.x * 8;
  if (e0 + 8 <= NEDGE) {
    int4 a = *(const int4*)(dst + e0);
    int4 b = *(const int4*)(dst + e0 + 4);
    atomicAdd(&hc[a.x >> 8], 1);
    atomicAdd(&hc[a.y >> 8], 1);
    atomicAdd(&hc[a.z >> 8], 1);
    atomicAdd(&hc[a.w >> 8], 1);
    atomicAdd(&hc[b.x >> 8], 1);
    atomicAdd(&hc[b.y >> 8], 1);
    atomicAdd(&hc[b.z >> 8], 1);
    atomicAdd(&hc[b.w >> 8], 1);
  } else {
    for (int e = e0; e < NEDGE; ++e) atomicAdd(&hc[dst[e] >> 8], 1);
  }
  __syncthreads();
  for (int t = threadIdx.x; t < NBUCK; t += 512) {
    int v = hc[t];
    if (v) atomicAdd(&bcnt[t], v);
  }
}

// ---------------------------------------------------------------------------
// scan: exclusive scan of 391 counts -> boff, gcursor; set sentinels.
// ---------------------------------------------------------------------------
__global__ __launch_bounds__(512) void scan_kernel(
    const int* __restrict__ bcnt, int* __restrict__ boff,
    int* __restrict__ gcursor, int* __restrict__ rowptr) {
  __shared__ int s[512];
  int v = (threadIdx.x < NBUCK) ? bcnt[threadIdx.x] : 0;
  s[threadIdx.x] = v;
  __syncthreads();
  for (int off = 1; off < 512; off <<= 1) {
    int t = (threadIdx.x >= off) ? s[threadIdx.x - off] : 0;
    __syncthreads();
    s[threadIdx.x] += t;
    __syncthreads();
  }
  if (threadIdx.x < NBUCK) {
    int e = s[threadIdx.x] - v;
    boff[threadIdx.x] = e;
    gcursor[threadIdx.x] = e;
  }
  if (threadIdx.x == 0) {
    boff[NBUCK] = NEDGE;
    rowptr[N_NODES] = NEDGE;
  }
}

// ---------------------------------------------------------------------------
// R15 partA: multi-split with LDS WRITE STAGING. After LDS-atomic ranks,
// block-scan cnt -> start[], stage recs bucket-sorted in LDS, then stream
// out so adjacent lanes write adjacent addresses (coalesced runs).
// rec = src | (dst&255)<<17. LDS ~31KB -> 4 blocks/CU (wave cap).
// ---------------------------------------------------------------------------
__global__ __launch_bounds__(512) void partA_kernel(
    const int* __restrict__ src, const int* __restrict__ dst,
    int* __restrict__ gcursor, unsigned* __restrict__ recs) {
  __shared__ int cnt[NBUCK];
  __shared__ int start[NBUCK];
  __shared__ int base[NBUCK];
  __shared__ int scn[512];
  __shared__ unsigned srec[4096];        // 16KB staged recs
  __shared__ unsigned short sbk[4096];   // 8KB bucket id per staged pos

  int tid = threadIdx.x;
  for (int t = tid; t < NBUCK; t += 512) cnt[t] = 0;
  __syncthreads();

  int ebase = blockIdx.x * 4096;
  int nblk = NEDGE - ebase;
  if (nblk > 4096) nblk = 4096;

  unsigned recv[8];
  int bk[8];
  int rank[8];
  int e0 = ebase + tid * 8;
  if (e0 + 8 <= NEDGE) {
    int4 d0 = *(const int4*)(dst + e0);
    int4 d1 = *(const int4*)(dst + e0 + 4);
    int4 s0 = *(const int4*)(src + e0);
    int4 s1 = *(const int4*)(src + e0 + 4);
    int dv[8] = {d0.x, d0.y, d0.z, d0.w, d1.x, d1.y, d1.z, d1.w};
    int sv[8] = {s0.x, s0.y, s0.z, s0.w, s1.x, s1.y, s1.z, s1.w};
#pragma unroll
    for (int k = 0; k < 8; ++k) {
      bk[k] = dv[k] >> 8;
      recv[k] = (unsigned)sv[k] | ((unsigned)(dv[k] & 255) << 17);
      rank[k] = atomicAdd(&cnt[bk[k]], 1);
    }
  } else {
#pragma unroll
    for (int k = 0; k < 8; ++k) {
      int e = e0 + k;
      if (e < NEDGE) {
        int d = dst[e];
        bk[k] = d >> 8;
        recv[k] = (unsigned)src[e] | ((unsigned)(d & 255) << 17);
        rank[k] = atomicAdd(&cnt[bk[k]], 1);
      } else {
        bk[k] = -1;
      }
    }
  }
  __syncthreads();

  // block exclusive scan of cnt -> start; reserve global base per bucket
  int v = (tid < NBUCK) ? cnt[tid] : 0;
  scn[tid] = v;
  __syncthreads();
  for (int off = 1; off < 512; off <<= 1) {
    int t = (tid >= off) ? scn[tid - off] : 0;
    __syncthreads();
    scn[tid] += t;
    __syncthreads();
  }
  if (tid < NBUCK) {
    start[tid] = scn[tid] - v;
    base[tid] = v ? atomicAdd(&gcursor[tid], v) : 0;
  }
  __syncthreads();

  // stage into bucket-sorted LDS
#pragma unroll
  for (int k = 0; k < 8; ++k) {
    if (bk[k] >= 0) {
      int pos = start[bk[k]] + rank[k];
      srec[pos] = recv[k];
      sbk[pos] = (unsigned short)bk[k];
    }
  }
  __syncthreads();

  // stream out: adjacent i -> adjacent global addr within each bucket run
  for (int i = tid; i < nblk; i += 512) {
    int b = sbk[i];
    recs[base[b] + (i - start[b])] = srec[i];
  }
}

// ---------------------------------------------------------------------------
// R15 sortB: per-bucket counting sort with LDS staged output; final write
// is a fully-coalesced linear stream. 1024 threads; 51KB LDS.
// ---------------------------------------------------------------------------
__global__ __launch_bounds__(1024) void sortB_kernel(
    const int* __restrict__ boff, const unsigned* __restrict__ recs,
    int* __restrict__ rowptr, int* __restrict__ colsrc) {
  __shared__ int hist[256];
  __shared__ int s[256];
  __shared__ int cur[256];
  __shared__ int staged[SCAP];  // 48KB
  if (threadIdx.x < 256) hist[threadIdx.x] = 0;
  __syncthreads();

  int b = blockIdx.x;
  int beg = boff[b], end = boff[b + 1];
  for (int j = beg + threadIdx.x; j < end; j += 1024)
    atomicAdd(&hist[recs[j] >> 17], 1);
  __syncthreads();

  if (threadIdx.x < 256) s[threadIdx.x] = hist[threadIdx.x];
  __syncthreads();
  for (int off = 1; off < 256; off <<= 1) {
    int t = 0;
    if (threadIdx.x < 256 && threadIdx.x >= off) t = s[threadIdx.x - off];
    __syncthreads();
    if (threadIdx.x < 256) s[threadIdx.x] += t;
    __syncthreads();
  }
  if (threadIdx.x < 256) {
    int excl = s[threadIdx.x] - hist[threadIdx.x];
    int n = b * 256 + threadIdx.x;
    if (n < N_NODES) rowptr[n] = beg + excl;
    cur[threadIdx.x] = excl;
  }
  __syncthreads();

  for (int j = beg + threadIdx.x; j < end; j += 1024) {
    unsigned r = recs[j];
    int dl = r >> 17;
    int pos = atomicAdd(&cur[dl], 1);
    if (pos < SCAP) staged[pos] = (int)(r & 0x1FFFF);
    else colsrc[beg + pos] = (int)(r & 0x1FFFF);  // overflow fallback (rare)
  }
  __syncthreads();

  int size = end - beg;
  if (size > SCAP) size = SCAP;
  for (int i = threadIdx.x; i < size; i += 1024) colsrc[beg + i] = staged[i];
}

// ---------------------------------------------------------------------------
// gather1: 8 lanes/node; lane bit0 = d (8-dim half, 16B request),
// bits1-2 = p (4-way edge interleave). fp32 accum; fused
// mean+xr1+b1+ELU -> h (fp32) and hb (bf16 table). (unchanged)
// ---------------------------------------------------------------------------
__global__ __launch_bounds__(256) void gather1_kernel(
    const int* __restrict__ rowptr, const int* __restrict__ colsrc,
    const uint4* __restrict__ valb8, const float4* __restrict__ xr14,
    const float* __restrict__ b1, float4* __restrict__ h4,
    uint4* __restrict__ hb8) {
  int t = blockIdx.x * 256 + threadIdx.x;
  int n = t >> 3;
  if (n >= N_NODES) return;
  int d = t & 1;
  int p = (t >> 1) & 3;
  int beg = rowptr[n], end = rowptr[n + 1];

  float a[8] = {0.f, 0.f, 0.f, 0.f, 0.f, 0.f, 0.f, 0.f};
  int bA = (beg + 3) & ~3;
  int eA = end & ~3;
  if (bA > eA) {
    if (p == 0)
      for (int j = beg; j < end; ++j) accum8(valb8[colsrc[j] * 2 + d], a);
  } else {
    if (p == 0) {
      for (int j = beg; j < bA; ++j) accum8(valb8[colsrc[j] * 2 + d], a);
    } else if (p == 3) {
      for (int j = eA; j < end; ++j) accum8(valb8[colsrc[j] * 2 + d], a);
    }
    float a1[8] = {0.f, 0.f, 0.f, 0.f, 0.f, 0.f, 0.f, 0.f};
    int j = bA + p * 4;
    for (; j + 20 <= eA; j += 32) {
      v4i c0 = __builtin_nontemporal_load((const v4i*)(colsrc + j));
      v4i c1 = __builtin_nontemporal_load((const v4i*)(colsrc + j + 16));
      uint4 w0 = valb8[c0.x * 2 + d];
      uint4 w1 = valb8[c0.y * 2 + d];
      uint4 w2 = valb8[c0.z * 2 + d];
      uint4 w3 = valb8[c0.w * 2 + d];
      uint4 w4 = valb8[c1.x * 2 + d];
      uint4 w5 = valb8[c1.y * 2 + d];
      uint4 w6 = valb8[c1.z * 2 + d];
      uint4 w7 = valb8[c1.w * 2 + d];
      accum8(w0, a);
      accum8(w1, a1);
      accum8(w2, a);
      accum8(w3, a1);
      accum8(w4, a);
      accum8(w5, a1);
      accum8(w6, a);
      accum8(w7, a1);
    }
    for (; j + 4 <= eA; j += 16) {
      v4i c0 = __builtin_nontemporal_load((const v4i*)(colsrc + j));
      accum8(valb8[c0.x * 2 + d], a);
      accum8(valb8[c0.y * 2 + d], a1);
      accum8(valb8[c0.z * 2 + d], a);
      accum8(valb8[c0.w * 2 + d], a1);
    }
#pragma unroll
    for (int k = 0; k < 8; ++k) a[k] += a1[k];
  }

#pragma unroll
  for (int k = 0; k < 8; ++k) {
    a[k] += __shfl_xor(a[k], 2);
    a[k] += __shfl_xor(a[k], 4);
  }
  if (p) return;

  float inv = 1.0f / fmaxf((float)(end - beg), 1.0f);
  float4 r0 = xr14[n * 4 + 2 * d];
  float4 r1 = xr14[n * 4 + 2 * d + 1];
  const float4* bb = (const float4*)b1;
  float4 bb0 = bb[2 * d], bb1 = bb[2 * d + 1];
  float o[8];
  o[0] = a[0] * inv + r0.x + bb0.x;
  o[1] = a[1] * inv + r0.y + bb0.y;
  o[2] = a[2] * inv + r0.z + bb0.z;
  o[3] = a[3] * inv + r0.w + bb0.w;
  o[4] = a[4] * inv + r1.x + bb1.x;
  o[5] = a[5] * inv + r1.y + bb1.y;
  o[6] = a[6] * inv + r1.z + bb1.z;
  o[7] = a[7] * inv + r1.w + bb1.w;
#pragma unroll
  for (int k = 0; k < 8; ++k) o[k] = (o[k] > 0.f) ? o[k] : expm1f(o[k]);
  h4[n * 4 + 2 * d] = make_float4(o[0], o[1], o[2], o[3]);
  h4[n * 4 + 2 * d + 1] = make_float4(o[4], o[5], o[6], o[7]);
  uint4 pk;
  pk.x = (unsigned)f2b(o[0]) | ((unsigned)f2b(o[1]) << 16);
  pk.y = (unsigned)f2b(o[2]) | ((unsigned)f2b(o[3]) << 16);
  pk.z = (unsigned)f2b(o[4]) | ((unsigned)f2b(o[5]) << 16);
  pk.w = (unsigned)f2b(o[6]) | ((unsigned)f2b(o[7]) << 16);
  hb8[n * 2 + d] = pk;
}

// ---------------------------------------------------------------------------
// gather2: same structure over hb; writes mean agg2n (fp32). (unchanged)
// ---------------------------------------------------------------------------
__global__ __launch_bounds__(256) void gather2_kernel(
    const int* __restrict__ rowptr, const int* __restrict__ colsrc,
    const uint4* __restrict__ valb8, float4* __restrict__ agg2n4) {
  int t = blockIdx.x * 256 + threadIdx.x;
  int n = t >> 3;
  if (n >= N_NODES) return;
  int d = t & 1;
  int p = (t >> 1) & 3;
  int beg = rowptr[n], end = rowptr[n + 1];

  float a[8] = {0.f, 0.f, 0.f, 0.f, 0.f, 0.f, 0.f, 0.f};
  int bA = (beg + 3) & ~3;
  int eA = end & ~3;
  if (bA > eA) {
    if (p == 0)
      for (int j = beg; j < end; ++j) accum8(valb8[colsrc[j] * 2 + d], a);
  } else {
    if (p == 0) {
      for (int j = beg; j < bA; ++j) accum8(valb8[colsrc[j] * 2 + d], a);
    } else if (p == 3) {
      for (int j = eA; j < end; ++j) accum8(valb8[colsrc[j] * 2 + d], a);
    }
    float a1[8] = {0.f, 0.f, 0.f, 0.f, 0.f, 0.f, 0.f, 0.f};
    int j = bA + p * 4;
    for (; j + 20 <= eA; j += 32) {
      v4i c0 = __builtin_nontemporal_load((const v4i*)(colsrc + j));
      v4i c1 = __builtin_nontemporal_load((const v4i*)(colsrc + j + 16));
      uint4 w0 = valb8[c0.x * 2 + d];
      uint4 w1 = valb8[c0.y * 2 + d];
      uint4 w2 = valb8[c0.z * 2 + d];
      uint4 w3 = valb8[c0.w * 2 + d];
      uint4 w4 = valb8[c1.x * 2 + d];
      uint4 w5 = valb8[c1.y * 2 + d];
      uint4 w6 = valb8[c1.z * 2 + d];
      uint4 w7 = valb8[c1.w * 2 + d];
      accum8(w0, a);
      accum8(w1, a1);
      accum8(w2, a);
      accum8(w3, a1);
      accum8(w4, a);
      accum8(w5, a1);
      accum8(w6, a);
      accum8(w7, a1);
    }
    for (; j + 4 <= eA; j += 16) {
      v4i c0 = __builtin_nontemporal_load((const v4i*)(colsrc + j));
      accum8(valb8[c0.x * 2 + d], a);
      accum8(valb8[c0.y * 2 + d], a1);
      accum8(valb8[c0.z * 2 + d], a);
      accum8(valb8[c0.w * 2 + d], a1);
    }
#pragma unroll
    for (int k = 0; k < 8; ++k) a[k] += a1[k];
  }

#pragma unroll
  for (int k = 0; k < 8; ++k) {
    a[k] += __shfl_xor(a[k], 2);
    a[k] += __shfl_xor(a[k], 4);
  }
  if (p) return;

  float inv = 1.0f / fmaxf((float)(end - beg), 1.0f);
  agg2n4[n * 4 + 2 * d] =
      make_float4(a[0] * inv, a[1] * inv, a[2] * inv, a[3] * inv);
  agg2n4[n * 4 + 2 * d + 1] =
      make_float4(a[4] * inv, a[5] * inv, a[6] * inv, a[7] * inv);
}

// ---------------------------------------------------------------------------
// out: agg2n @ W2[1] + h @ root2 + b2, log_softmax, fp32 store. (unchanged)
// ---------------------------------------------------------------------------
__global__ __launch_bounds__(256) void out_kernel(
    const float* __restrict__ h, const float* __restrict__ agg2n,
    const float* __restrict__ W2, const float* __restrict__ root2,
    const float* __restrict__ b2v, float* __restrict__ out) {
  __shared__ float Wl[HID * NCLS];
  __shared__ float Rl[HID * NCLS];
  __shared__ float Bl[NCLS];
  for (int i = threadIdx.x; i < HID * NCLS; i += blockDim.x) {
    Wl[i] = W2[HID * NCLS + i];
    Rl[i] = root2[i];
  }
  if (threadIdx.x < NCLS) Bl[threadIdx.x] = b2v[threadIdx.x];
  __syncthreads();

  int n = blockIdx.x * blockDim.x + threadIdx.x;
  if (n >= N_NODES) return;

  float hv[HID], av[HID];
#pragma unroll
  for (int c = 0; c < HID; ++c) {
    hv[c] = h[n * HID + c];
    av[c] = agg2n[n * HID + c];
  }
  float logit[NCLS];
#pragma unroll
  for (int j = 0; j < NCLS; ++j) logit[j] = Bl[j];
  for (int c = 0; c < HID; ++c) {
    float hc = hv[c], ac = av[c];
#pragma unroll
    for (int j = 0; j < NCLS; ++j)
      logit[j] += ac * Wl[c * NCLS + j] + hc * Rl[c * NCLS + j];
  }
  float m = -INFINITY;
#pragma unroll
  for (int j = 0; j < NCLS; ++j) m = fmaxf(m, logit[j]);
  float s = 0.f;
#pragma unroll
  for (int j = 0; j < NCLS; ++j) s += expf(logit[j] - m);
  float lse = m + logf(s);
#pragma unroll
  for (int j = 0; j < NCLS; ++j)
    out[(size_t)n * NCLS + j] = logit[j] - lse;
}

extern "C" void kernel_launch(void* const* d_in, const int* in_sizes, int n_in,
                              void* d_out, int out_size, void* d_ws,
                              size_t ws_size, hipStream_t stream) {
  const float* x = (const float*)d_in[0];
  const int* ei = (const int*)d_in[1];  // (2, E): src row then dst row
  const float* W1 = (const float*)d_in[2];
  const float* root1 = (const float*)d_in[3];
  const float* b1 = (const float*)d_in[4];
  const float* W2 = (const float*)d_in[5];
  const float* root2 = (const float*)d_in[6];
  const float* b2v = (const float*)d_in[7];
  float* out = (float*)d_out;

  const int* src = ei;
  const int* dstp = ei + NEDGE;

  // workspace (bytes):
  // [bcnt 2K][boff 2K][gcursor 2K][rowptr (N+4)*4]
  // [recs E*4  (lower half reused as h fp32, upper half as agg2n fp32)]
  // [colsrc E*4][xw1b 16N*2][xr1 16N*4][hb 16N*2]
  char* w = (char*)d_ws;
  int* bcnt = (int*)w;           w += 2048;
  int* boff = (int*)w;           w += 2048;
  int* gcursor = (int*)w;        w += 2048;
  int* rowptr = (int*)w;         w += (size_t)(N_NODES + 4) * 4;
  unsigned* recs = (unsigned*)w; w += (size_t)NEDGE * 4;
  int* colsrc = (int*)w;         w += (size_t)NEDGE * 4;
  unsigned* xw1b = (unsigned*)w; w += (size_t)N_NODES * HID * 2;
  float* xr1 = (float*)w;        w += (size_t)N_NODES * HID * 4;
  unsigned short* hb = (unsigned short*)w; w += (size_t)N_NODES * HID * 2;

  float* h = (float*)recs;  // recs dead after sortB; h = 6.4MB (half of recs)
  float* agg2n = (float*)((char*)recs + (size_t)N_NODES * HID * 4);

  hipMemsetAsync(bcnt, 0, 2048, stream);

  proj1_kernel<<<(N_NODES + 63) / 64, 256, 0, stream>>>(x, W1, root1, xw1b,
                                                        xr1);
  histB_kernel<<<NCHUNK, 512, 0, stream>>>(dstp, bcnt);
  scan_kernel<<<1, 512, 0, stream>>>(bcnt, boff, gcursor, rowptr);
  partA_kernel<<<NCHUNK, 512, 0, stream>>>(src, dstp, gcursor, recs);
  sortB_kernel<<<NBUCK, 1024, 0, stream>>>(boff, recs, rowptr, colsrc);
  gather1_kernel<<<(N_NODES * 8 + 255) / 256, 256, 0, stream>>>(
      rowptr, colsrc, (const uint4*)xw1b, (const float4*)xr1, b1, (float4*)h,
      (uint4*)hb);
  gather2_kernel<<<(N_NODES * 8 + 255) / 256, 256, 0, stream>>>(
      rowptr, colsrc, (const uint4*)hb, (float4*)agg2n);
  out_kernel<<<(N_NODES + 255) / 256, 256, 0, stream>>>(h, agg2n, W2, root2,
                                                        b2v, out);
}